// Round 1
// baseline (742.058 us; speedup 1.0000x reference)
//
#include <hip/hip_runtime.h>
#include <hip/hip_bf16.h>

// ---------------- CSR build ----------------

__global__ void count_kernel(const int* __restrict__ dst, int* __restrict__ count, int E) {
    int e = blockIdx.x * blockDim.x + threadIdx.x;
    if (e < E) atomicAdd(&count[dst[e]], 1);
}

// block-level inclusive scan (1024 threads/block); also computes dinv = rsqrt(deg+1)
__global__ void scan1_kernel(const int* __restrict__ count, int* __restrict__ incl,
                             float* __restrict__ dinv, int* __restrict__ blocksum, int n) {
    __shared__ int lds[1024];
    int t = threadIdx.x;
    int i = blockIdx.x * 1024 + t;
    int v = (i < n) ? count[i] : 0;
    if (i < n) dinv[i] = rsqrtf((float)(v + 1));
    lds[t] = v;
    __syncthreads();
    for (int off = 1; off < 1024; off <<= 1) {
        int add = (t >= off) ? lds[t - off] : 0;
        __syncthreads();
        lds[t] += add;
        __syncthreads();
    }
    if (i < n) incl[i] = lds[t];
    if (t == 1023) blocksum[blockIdx.x] = lds[1023];
}

__global__ void scan2_kernel(const int* __restrict__ blocksum, int* __restrict__ blockoff,
                             int* __restrict__ rowptr, int nb, int n, int E) {
    __shared__ int lds[1024];
    int t = threadIdx.x;
    int v = (t < nb) ? blocksum[t] : 0;
    lds[t] = v;
    __syncthreads();
    for (int off = 1; off < 1024; off <<= 1) {
        int add = (t >= off) ? lds[t - off] : 0;
        __syncthreads();
        lds[t] += add;
        __syncthreads();
    }
    if (t < nb) blockoff[t] = lds[t] - v;   // exclusive
    if (t == 0) rowptr[n] = E;
}

__global__ void scan3_kernel(int* __restrict__ rowptr, const int* __restrict__ count,
                             const int* __restrict__ blockoff, int n) {
    int i = blockIdx.x * blockDim.x + threadIdx.x;
    if (i < n) rowptr[i] = rowptr[i] - count[i] + blockoff[i >> 10];
}

__global__ void scatter_kernel(const int* __restrict__ src, const int* __restrict__ dst,
                               const int* __restrict__ rowptr, int* __restrict__ cursor,
                               int* __restrict__ esrc, int E) {
    int e = blockIdx.x * blockDim.x + threadIdx.x;
    if (e < E) {
        int d = dst[e];
        int pos = rowptr[d] + atomicAdd(&cursor[d], 1);
        esrc[pos] = src[e];
    }
}

// ---------------- GEMM with dinv-scaled epilogue: G = (X @ W) * dinv[row] ----------------
// X: [n, DIN] row-major, W: [DIN, DOUT] row-major, G: [n, DOUT]
template<int DIN, int DOUT>
__global__ __launch_bounds__(256) void matmul_scale_kernel(
        const float* __restrict__ X, const float* __restrict__ W,
        const float* __restrict__ dinv, float* __restrict__ G, int n) {
    constexpr int BM = 64, BK = 64;
    constexpr int CPT = DOUT / 32;       // cols per thread (4 / 2 / 1)
    __shared__ float Xs[BM][BK + 4];     // +4 pad keeps float4 alignment
    __shared__ float Ws[BK][DOUT];
    int tid = threadIdx.x;
    int tx = tid & 31;                   // col group
    int ty = tid >> 5;                   // row group (8 rows each)
    int row0 = blockIdx.x * BM;

    float acc[8][CPT];
    #pragma unroll
    for (int r = 0; r < 8; r++)
        #pragma unroll
        for (int c = 0; c < CPT; c++) acc[r][c] = 0.f;

    for (int k0 = 0; k0 < DIN; k0 += BK) {
        for (int i = tid; i < BM * (BK / 4); i += 256) {
            int r = i >> 4, c4 = (i & 15) << 2;
            int rg = row0 + r;
            float4 v = make_float4(0.f, 0.f, 0.f, 0.f);
            if (rg < n) v = *(const float4*)&X[(size_t)rg * DIN + k0 + c4];
            *(float4*)&Xs[r][c4] = v;
        }
        for (int i = tid; i < BK * (DOUT / 4); i += 256) {
            int r = i / (DOUT / 4), c4 = (i % (DOUT / 4)) << 2;
            *(float4*)&Ws[r][c4] = *(const float4*)&W[(size_t)(k0 + r) * DOUT + c4];
        }
        __syncthreads();
        #pragma unroll 4
        for (int k = 0; k < BK; k++) {
            float xv[8];
            #pragma unroll
            for (int r = 0; r < 8; r++) xv[r] = Xs[ty * 8 + r][k];
            float wv[CPT];
            #pragma unroll
            for (int c = 0; c < CPT; c++) wv[c] = Ws[k][tx + 32 * c];
            #pragma unroll
            for (int r = 0; r < 8; r++)
                #pragma unroll
                for (int c = 0; c < CPT; c++)
                    acc[r][c] += xv[r] * wv[c];
        }
        __syncthreads();
    }
    #pragma unroll
    for (int r = 0; r < 8; r++) {
        int rg = row0 + ty * 8 + r;
        if (rg < n) {
            float di = dinv[rg];
            #pragma unroll
            for (int c = 0; c < CPT; c++)
                G[(size_t)rg * DOUT + tx + 32 * c] = acc[r][c] * di;
        }
    }
}

// ---------------- aggregation: out[i] = tanh(dinv[i]*(sum_e g[src_e] + g[i]) + b) ----------------
template<int DOUT>
__global__ void agg_kernel(const float* __restrict__ g, const float* __restrict__ dinv,
                           const int* __restrict__ rowptr, const int* __restrict__ esrc,
                           const float* __restrict__ bias, float* __restrict__ out, int n) {
    constexpr int CPL = (DOUT + 63) / 64;   // cols per lane
    constexpr int LPN = DOUT / CPL;         // lanes per node (64 or 32)
    constexpr int NPW = 64 / LPN;           // nodes per wave (1 or 2)
    int wave = threadIdx.x >> 6;
    int lane = threadIdx.x & 63;
    int sub = lane / LPN;
    int cl  = lane % LPN;
    int node = (blockIdx.x * (blockDim.x >> 6) + wave) * NPW + sub;
    if (node >= n) return;

    float acc[CPL];
    #pragma unroll
    for (int c = 0; c < CPL; c++) acc[c] = g[(size_t)node * DOUT + cl + c * LPN];

    int e = rowptr[node], end = rowptr[node + 1];
    for (; e + 3 < end; e += 4) {
        int s0 = esrc[e], s1 = esrc[e + 1], s2 = esrc[e + 2], s3 = esrc[e + 3];
        #pragma unroll
        for (int c = 0; c < CPL; c++) {
            acc[c] += g[(size_t)s0 * DOUT + cl + c * LPN];
            acc[c] += g[(size_t)s1 * DOUT + cl + c * LPN];
            acc[c] += g[(size_t)s2 * DOUT + cl + c * LPN];
            acc[c] += g[(size_t)s3 * DOUT + cl + c * LPN];
        }
    }
    for (; e < end; e++) {
        int s = esrc[e];
        #pragma unroll
        for (int c = 0; c < CPL; c++) acc[c] += g[(size_t)s * DOUT + cl + c * LPN];
    }
    float di = dinv[node];
    #pragma unroll
    for (int c = 0; c < CPL; c++) {
        float v = di * acc[c] + bias[cl + c * LPN];
        out[(size_t)node * DOUT + cl + c * LPN] = tanhf(v);
    }
}

// ---------------- classifier: out = H @ Wc + bc  (32 -> 86) ----------------
__global__ __launch_bounds__(256) void cls_kernel(
        const float* __restrict__ H, const float* __restrict__ Wc,
        const float* __restrict__ bc, float* __restrict__ out, int n) {
    constexpr int DIN = 32, DOUT = 86, RPB = 64;
    __shared__ float Hs[RPB][DIN + 4];
    __shared__ float Ws[DIN][DOUT];
    __shared__ float bs[DOUT];
    int tid = threadIdx.x;
    int row0 = blockIdx.x * RPB;
    for (int i = tid; i < DIN * DOUT; i += 256) Ws[i / DOUT][i % DOUT] = Wc[i];
    if (tid < DOUT) bs[tid] = bc[tid];
    for (int i = tid; i < RPB * (DIN / 4); i += 256) {
        int r = i >> 3, c4 = (i & 7) << 2;
        int rg = row0 + r;
        float4 v = make_float4(0.f, 0.f, 0.f, 0.f);
        if (rg < n) v = *(const float4*)&H[(size_t)rg * DIN + c4];
        *(float4*)&Hs[r][c4] = v;
    }
    __syncthreads();
    for (int idx = tid; idx < RPB * DOUT; idx += 256) {
        int r = idx / DOUT, c = idx - r * DOUT;
        float a = bs[c];
        #pragma unroll
        for (int k = 0; k < DIN; k++) a += Hs[r][k] * Ws[k][c];
        int rg = row0 + r;
        if (rg < n) out[(size_t)rg * DOUT + c] = a;
    }
}

extern "C" void kernel_launch(void* const* d_in, const int* in_sizes, int n_in,
                              void* d_out, int out_size, void* d_ws, size_t ws_size,
                              hipStream_t stream) {
    const float* x  = (const float*)d_in[0];
    const int*   ei = (const int*)d_in[1];
    const float* W1 = (const float*)d_in[2];
    const float* b1 = (const float*)d_in[3];
    const float* W2 = (const float*)d_in[4];
    const float* b2 = (const float*)d_in[5];
    const float* W3 = (const float*)d_in[6];
    const float* b3 = (const float*)d_in[7];
    const float* Wc = (const float*)d_in[8];
    const float* bc = (const float*)d_in[9];

    const int n = in_sizes[0] / 256;     // 100000
    const int E = in_sizes[1] / 2;       // 1600000
    const int* src = ei;
    const int* dst = ei + E;

    char* ws = (char*)d_ws;
    size_t off = 0;
    auto alloc = [&](size_t bytes) {
        void* p = ws + off;
        off = (off + bytes + 255) & ~(size_t)255;
        return p;
    };
    float* dinv    = (float*)alloc((size_t)n * 4);
    int*   count   = (int*)  alloc((size_t)n * 4);
    int*   rowptr  = (int*)  alloc((size_t)(n + 1) * 4);
    int*   cursor  = (int*)  alloc((size_t)n * 4);
    int*   blocksum= (int*)  alloc(1024 * 4);
    int*   blockoff= (int*)  alloc(1024 * 4);
    int*   esrc    = (int*)  alloc((size_t)E * 4);
    float* bufA    = (float*)alloc((size_t)n * 128 * 4);
    float* bufB    = (float*)alloc((size_t)n * 128 * 4);

    float* outp = (float*)d_out;             // [n, 86]
    float* h3   = outp + (size_t)n * 86;     // [n, 32] (second tuple output)

    hipMemsetAsync(count, 0, (size_t)n * 4, stream);
    hipMemsetAsync(cursor, 0, (size_t)n * 4, stream);

    int eblocks = (E + 255) / 256;
    count_kernel<<<eblocks, 256, 0, stream>>>(dst, count, E);
    int nb = (n + 1023) / 1024;
    scan1_kernel<<<nb, 1024, 0, stream>>>(count, rowptr, dinv, blocksum, n);
    scan2_kernel<<<1, 1024, 0, stream>>>(blocksum, blockoff, rowptr, nb, n, E);
    scan3_kernel<<<(n + 255) / 256, 256, 0, stream>>>(rowptr, count, blockoff, n);
    scatter_kernel<<<eblocks, 256, 0, stream>>>(src, dst, rowptr, cursor, esrc, E);

    int mblocks = (n + 63) / 64;
    // layer 1: 256 -> 128
    matmul_scale_kernel<256, 128><<<mblocks, 256, 0, stream>>>(x, W1, dinv, bufA, n);
    agg_kernel<128><<<(n + 3) / 4, 256, 0, stream>>>(bufA, dinv, rowptr, esrc, b1, bufB, n);
    // layer 2: 128 -> 64
    matmul_scale_kernel<128, 64><<<mblocks, 256, 0, stream>>>(bufB, W2, dinv, bufA, n);
    agg_kernel<64><<<(n + 3) / 4, 256, 0, stream>>>(bufA, dinv, rowptr, esrc, b2, bufB, n);
    // layer 3: 64 -> 32
    matmul_scale_kernel<64, 32><<<mblocks, 256, 0, stream>>>(bufB, W3, dinv, bufA, n);
    agg_kernel<32><<<(n + 7) / 8, 256, 0, stream>>>(bufA, dinv, rowptr, esrc, b3, h3, n);
    // classifier: 32 -> 86
    cls_kernel<<<(n + 63) / 64, 256, 0, stream>>>(h3, Wc, bc, outp, n);
}

// Round 2
// 709.716 us; speedup vs baseline: 1.0456x; 1.0456x over previous
//
#include <hip/hip_runtime.h>
#include <hip/hip_bf16.h>

// ---------------- CSR build ----------------

__global__ void count_kernel(const int* __restrict__ dst, int* __restrict__ count, int E) {
    int e = blockIdx.x * blockDim.x + threadIdx.x;
    if (e < E) atomicAdd(&count[dst[e]], 1);
}

// block-level inclusive scan (1024 threads/block); also computes dinv = rsqrt(deg+1)
__global__ void scan1_kernel(const int* __restrict__ count, int* __restrict__ incl,
                             float* __restrict__ dinv, int* __restrict__ blocksum, int n) {
    __shared__ int lds[1024];
    int t = threadIdx.x;
    int i = blockIdx.x * 1024 + t;
    int v = (i < n) ? count[i] : 0;
    if (i < n) dinv[i] = rsqrtf((float)(v + 1));
    lds[t] = v;
    __syncthreads();
    for (int off = 1; off < 1024; off <<= 1) {
        int add = (t >= off) ? lds[t - off] : 0;
        __syncthreads();
        lds[t] += add;
        __syncthreads();
    }
    if (i < n) incl[i] = lds[t];
    if (t == 1023) blocksum[blockIdx.x] = lds[1023];
}

__global__ void scan2_kernel(const int* __restrict__ blocksum, int* __restrict__ blockoff,
                             int* __restrict__ rowptr, int nb, int n, int E) {
    __shared__ int lds[1024];
    int t = threadIdx.x;
    int v = (t < nb) ? blocksum[t] : 0;
    lds[t] = v;
    __syncthreads();
    for (int off = 1; off < 1024; off <<= 1) {
        int add = (t >= off) ? lds[t - off] : 0;
        __syncthreads();
        lds[t] += add;
        __syncthreads();
    }
    if (t < nb) blockoff[t] = lds[t] - v;   // exclusive
    if (t == 0) rowptr[n] = E;
}

__global__ void scan3_kernel(int* __restrict__ rowptr, const int* __restrict__ count,
                             const int* __restrict__ blockoff, int n) {
    int i = blockIdx.x * blockDim.x + threadIdx.x;
    if (i < n) rowptr[i] = rowptr[i] - count[i] + blockoff[i >> 10];
}

__global__ void scatter_kernel(const int* __restrict__ src, const int* __restrict__ dst,
                               const int* __restrict__ rowptr, int* __restrict__ cursor,
                               int* __restrict__ esrc, int E) {
    int e = blockIdx.x * blockDim.x + threadIdx.x;
    if (e < E) {
        int d = dst[e];
        int pos = rowptr[d] + atomicAdd(&cursor[d], 1);
        esrc[pos] = src[e];
    }
}

// ---------------- GEMM with dinv-scaled epilogue: G = (X @ W) * dinv[row] ----------------
// X: [n, DIN] row-major, W: [DIN, DOUT] row-major, G: [n, DOUT]
// Register-tiled: thread tile TM(=8) x TN; X staged TRANSPOSED in LDS (XOR-swizzled
// rows: 2-way write conflicts = free) so fragment reads are ds_read_b128.
template<int DIN, int DOUT, int TN>
__global__ __launch_bounds__(256) void matmul_scale_kernel(
        const float* __restrict__ X, const float* __restrict__ W,
        const float* __restrict__ dinv, float* __restrict__ G, int n) {
    constexpr int TM = 8;
    constexpr int NCG = DOUT / TN;        // col groups (threads along N)
    constexpr int NRG = 256 / NCG;        // row groups
    constexpr int BM = NRG * TM;          // 128 (L1,L2) or 256 (L3)
    constexpr int BK = 32;
    constexpr int XS = BM + 4;            // padded stride (float4-aligned)

    __shared__ float Xt[BK][XS];          // transposed X tile, row-swizzled
    __shared__ float Ws[BK][DOUT];

    int tid = threadIdx.x;
    int tx = tid % NCG;                   // col group -> cols [tx*TN, tx*TN+TN)
    int ty = tid / NCG;                   // row group -> rows [ty*TM, ty*TM+TM)
    int row0 = blockIdx.x * BM;

    float acc[TM][TN];
    #pragma unroll
    for (int r = 0; r < TM; r++)
        #pragma unroll
        for (int c = 0; c < TN; c++) acc[r][c] = 0.f;

    for (int k0 = 0; k0 < DIN; k0 += BK) {
        // stage X transposed: logical Xt[k][r] stored at Xt[k][r ^ (((k>>2)&3)<<3)]
        #pragma unroll
        for (int i = tid; i < BM * (BK / 4); i += 256) {
            int r  = i >> 3;              // tile row 0..BM-1
            int c4 = (i & 7) << 2;        // k offset 0,4,...,28
            int rg = row0 + r;
            float4 v = make_float4(0.f, 0.f, 0.f, 0.f);
            if (rg < n) v = *(const float4*)&X[(size_t)rg * DIN + k0 + c4];
            const float* vp = (const float*)&v;
            #pragma unroll
            for (int j = 0; j < 4; j++) {
                int c  = c4 + j;
                int rs = r ^ (((c >> 2) & 3) << 3);
                Xt[c][rs] = vp[j];
            }
        }
        // stage W row-major
        #pragma unroll
        for (int i = tid; i < BK * (DOUT / 4); i += 256) {
            int r  = i / (DOUT / 4);
            int c4 = (i % (DOUT / 4)) << 2;
            *(float4*)&Ws[r][c4] = *(const float4*)&W[(size_t)(k0 + r) * DOUT + c4];
        }
        __syncthreads();

        #pragma unroll 4
        for (int k = 0; k < BK; k++) {
            int mask = ((k >> 2) & 3) << 3;
            int rr = (ty * TM) ^ mask;    // 8-aligned physical row block
            float xv[TM];
            *(float4*)&xv[0] = *(const float4*)&Xt[k][rr];
            *(float4*)&xv[4] = *(const float4*)&Xt[k][rr + 4];
            float wv[TN];
            #pragma unroll
            for (int c4 = 0; c4 < TN; c4 += 4)
                *(float4*)&wv[c4] = *(const float4*)&Ws[k][tx * TN + c4];
            #pragma unroll
            for (int r = 0; r < TM; r++)
                #pragma unroll
                for (int c = 0; c < TN; c++)
                    acc[r][c] += xv[r] * wv[c];
        }
        __syncthreads();
    }

    #pragma unroll
    for (int r = 0; r < TM; r++) {
        int rg = row0 + ty * TM + r;
        if (rg < n) {
            float di = dinv[rg];
            float ov[TN];
            #pragma unroll
            for (int c = 0; c < TN; c++) ov[c] = acc[r][c] * di;
            #pragma unroll
            for (int c4 = 0; c4 < TN; c4 += 4)
                *(float4*)&G[(size_t)rg * DOUT + tx * TN + c4] = *(float4*)&ov[c4];
        }
    }
}

// ---------------- aggregation: out[i] = tanh(dinv[i]*(sum_e g[src_e] + g[i]) + b) ----------------
// float2 lanes: DOUT/2 lanes per node, b64 gathers.
template<int DOUT>
__global__ void agg_kernel(const float* __restrict__ g, const float* __restrict__ dinv,
                           const int* __restrict__ rowptr, const int* __restrict__ esrc,
                           const float* __restrict__ bias, float* __restrict__ out, int n) {
    constexpr int LPN = DOUT / 2;           // lanes per node (float2 each)
    constexpr int NPW = 64 / LPN;           // nodes per wave
    int wave = threadIdx.x >> 6;
    int lane = threadIdx.x & 63;
    int sub  = lane / LPN;
    int cl   = lane % LPN;                  // float2 column index
    int node = (blockIdx.x * (blockDim.x >> 6) + wave) * NPW + sub;
    if (node >= n) return;

    const float2* g2 = (const float2*)g;
    float2 acc = g2[(size_t)node * LPN + cl];     // self-loop term

    int e = rowptr[node], end = rowptr[node + 1];
    for (; e + 4 <= end; e += 4) {
        int s0 = esrc[e], s1 = esrc[e + 1], s2 = esrc[e + 2], s3 = esrc[e + 3];
        float2 v0 = g2[(size_t)s0 * LPN + cl];
        float2 v1 = g2[(size_t)s1 * LPN + cl];
        float2 v2 = g2[(size_t)s2 * LPN + cl];
        float2 v3 = g2[(size_t)s3 * LPN + cl];
        acc.x += v0.x + v1.x + v2.x + v3.x;
        acc.y += v0.y + v1.y + v2.y + v3.y;
    }
    for (; e < end; e++) {
        int s = esrc[e];
        float2 v = g2[(size_t)s * LPN + cl];
        acc.x += v.x;
        acc.y += v.y;
    }
    float di = dinv[node];
    float2 b = ((const float2*)bias)[cl];
    float2 o;
    o.x = tanhf(di * acc.x + b.x);
    o.y = tanhf(di * acc.y + b.y);
    ((float2*)out)[(size_t)node * LPN + cl] = o;
}

// ---------------- classifier: out = H @ Wc + bc  (32 -> 86) ----------------
__global__ __launch_bounds__(256) void cls_kernel(
        const float* __restrict__ H, const float* __restrict__ Wc,
        const float* __restrict__ bc, float* __restrict__ out, int n) {
    constexpr int DIN = 32, DOUT = 86, RPB = 64;
    __shared__ float Hs[RPB][DIN + 4];
    __shared__ float Ws[DIN][DOUT];
    __shared__ float bs[DOUT];
    int tid = threadIdx.x;
    int row0 = blockIdx.x * RPB;
    for (int i = tid; i < DIN * DOUT; i += 256) Ws[i / DOUT][i % DOUT] = Wc[i];
    if (tid < DOUT) bs[tid] = bc[tid];
    for (int i = tid; i < RPB * (DIN / 4); i += 256) {
        int r = i >> 3, c4 = (i & 7) << 2;
        int rg = row0 + r;
        float4 v = make_float4(0.f, 0.f, 0.f, 0.f);
        if (rg < n) v = *(const float4*)&H[(size_t)rg * DIN + c4];
        *(float4*)&Hs[r][c4] = v;
    }
    __syncthreads();
    for (int idx = tid; idx < RPB * DOUT; idx += 256) {
        int r = idx / DOUT, c = idx - r * DOUT;
        float a = bs[c];
        #pragma unroll
        for (int k = 0; k < DIN; k++) a += Hs[r][k] * Ws[k][c];
        int rg = row0 + r;
        if (rg < n) out[(size_t)rg * DOUT + c] = a;
    }
}

extern "C" void kernel_launch(void* const* d_in, const int* in_sizes, int n_in,
                              void* d_out, int out_size, void* d_ws, size_t ws_size,
                              hipStream_t stream) {
    const float* x  = (const float*)d_in[0];
    const int*   ei = (const int*)d_in[1];
    const float* W1 = (const float*)d_in[2];
    const float* b1 = (const float*)d_in[3];
    const float* W2 = (const float*)d_in[4];
    const float* b2 = (const float*)d_in[5];
    const float* W3 = (const float*)d_in[6];
    const float* b3 = (const float*)d_in[7];
    const float* Wc = (const float*)d_in[8];
    const float* bc = (const float*)d_in[9];

    const int n = in_sizes[0] / 256;     // 100000
    const int E = in_sizes[1] / 2;       // 1600000
    const int* src = ei;
    const int* dst = ei + E;

    char* ws = (char*)d_ws;
    size_t off = 0;
    auto alloc = [&](size_t bytes) {
        void* p = ws + off;
        off = (off + bytes + 255) & ~(size_t)255;
        return p;
    };
    float* dinv    = (float*)alloc((size_t)n * 4);
    int*   count   = (int*)  alloc((size_t)n * 4);
    int*   rowptr  = (int*)  alloc((size_t)(n + 1) * 4);
    int*   cursor  = (int*)  alloc((size_t)n * 4);
    int*   blocksum= (int*)  alloc(1024 * 4);
    int*   blockoff= (int*)  alloc(1024 * 4);
    int*   esrc    = (int*)  alloc((size_t)E * 4);
    float* bufA    = (float*)alloc((size_t)n * 128 * 4);
    float* bufB    = (float*)alloc((size_t)n * 128 * 4);

    float* outp = (float*)d_out;             // [n, 86]
    float* h3   = outp + (size_t)n * 86;     // [n, 32] (second tuple output)

    hipMemsetAsync(count, 0, (size_t)n * 4, stream);
    hipMemsetAsync(cursor, 0, (size_t)n * 4, stream);

    int eblocks = (E + 255) / 256;
    count_kernel<<<eblocks, 256, 0, stream>>>(dst, count, E);
    int nb = (n + 1023) / 1024;
    scan1_kernel<<<nb, 1024, 0, stream>>>(count, rowptr, dinv, blocksum, n);
    scan2_kernel<<<1, 1024, 0, stream>>>(blocksum, blockoff, rowptr, nb, n, E);
    scan3_kernel<<<(n + 255) / 256, 256, 0, stream>>>(rowptr, count, blockoff, n);
    scatter_kernel<<<eblocks, 256, 0, stream>>>(src, dst, rowptr, cursor, esrc, E);

    // layer 1: 256 -> 128   (BM=128)
    matmul_scale_kernel<256, 128, 8><<<(n + 127) / 128, 256, 0, stream>>>(x, W1, dinv, bufA, n);
    agg_kernel<128><<<(n + 3) / 4, 256, 0, stream>>>(bufA, dinv, rowptr, esrc, b1, bufB, n);
    // layer 2: 128 -> 64    (BM=128)
    matmul_scale_kernel<128, 64, 4><<<(n + 127) / 128, 256, 0, stream>>>(bufB, W2, dinv, bufA, n);
    agg_kernel<64><<<(n + 7) / 8, 256, 0, stream>>>(bufA, dinv, rowptr, esrc, b2, bufB, n);
    // layer 3: 64 -> 32     (BM=256)
    matmul_scale_kernel<64, 32, 4><<<(n + 255) / 256, 256, 0, stream>>>(bufB, W3, dinv, bufA, n);
    agg_kernel<32><<<(n + 15) / 16, 256, 0, stream>>>(bufA, dinv, rowptr, esrc, b3, h3, n);
    // classifier: 32 -> 86
    cls_kernel<<<(n + 63) / 64, 256, 0, stream>>>(h3, Wc, bc, outp, n);
}

// Round 6
// 682.659 us; speedup vs baseline: 1.0870x; 1.0396x over previous
//
#include <hip/hip_runtime.h>
#include <hip/hip_bf16.h>
#include <hip/hip_fp16.h>

// ---------------- CSR build ----------------

__global__ void count_kernel(const int* __restrict__ dst, int* __restrict__ count, int E) {
    int e = blockIdx.x * blockDim.x + threadIdx.x;
    if (e < E) atomicAdd(&count[dst[e]], 1);
}

__global__ void scan1_kernel(const int* __restrict__ count, int* __restrict__ incl,
                             float* __restrict__ dinv, int* __restrict__ blocksum, int n) {
    __shared__ int lds[1024];
    int t = threadIdx.x;
    int i = blockIdx.x * 1024 + t;
    int v = (i < n) ? count[i] : 0;
    if (i < n) dinv[i] = rsqrtf((float)(v + 1));
    lds[t] = v;
    __syncthreads();
    for (int off = 1; off < 1024; off <<= 1) {
        int add = (t >= off) ? lds[t - off] : 0;
        __syncthreads();
        lds[t] += add;
        __syncthreads();
    }
    if (i < n) incl[i] = lds[t];
    if (t == 1023) blocksum[blockIdx.x] = lds[1023];
}

__global__ void scan2_kernel(const int* __restrict__ blocksum, int* __restrict__ blockoff,
                             int* __restrict__ rowptr, int nb, int n, int E) {
    __shared__ int lds[1024];
    int t = threadIdx.x;
    int v = (t < nb) ? blocksum[t] : 0;
    lds[t] = v;
    __syncthreads();
    for (int off = 1; off < 1024; off <<= 1) {
        int add = (t >= off) ? lds[t - off] : 0;
        __syncthreads();
        lds[t] += add;
        __syncthreads();
    }
    if (t < nb) blockoff[t] = lds[t] - v;   // exclusive
    if (t == 0) rowptr[n] = E;
}

__global__ void scan3_kernel(int* __restrict__ rowptr, const int* __restrict__ count,
                             const int* __restrict__ blockoff, int n) {
    int i = blockIdx.x * blockDim.x + threadIdx.x;
    if (i < n) rowptr[i] = rowptr[i] - count[i] + blockoff[i >> 10];
}

__global__ void scatter_kernel(const int* __restrict__ src, const int* __restrict__ dst,
                               const int* __restrict__ rowptr, int* __restrict__ cursor,
                               int* __restrict__ esrc, int E) {
    int e = blockIdx.x * blockDim.x + threadIdx.x;
    if (e < E) {
        int d = dst[e];
        int pos = rowptr[d] + atomicAdd(&cursor[d], 1);
        esrc[pos] = src[e];
    }
}

// ---------------- GEMM with dinv-scaled epilogue, fp16 output ----------------
// G = half( (X @ W) * dinv[row] ).  X [n,DIN] f32 row-major, W [DIN,DOUT] f32.
// Thread tile 8 x (4*QN); the QN col-quads are DOUT/2 apart so W fragment reads
// are 2-way bank aliases (free). X staged transposed + XOR-swizzled (conflict-free
// stores and reads, verified by bank arithmetic; R2's 7.2M conflicts were W reads).
template<int DIN, int DOUT, int QN, int BM>
__global__ __launch_bounds__(128) void matmul_scale_kernel(
        const float* __restrict__ X, const float* __restrict__ W,
        const float* __restrict__ dinv, __half* __restrict__ G, int n) {
    constexpr int TM = 8;
    constexpr int NCG = DOUT / (4 * QN);  // threads along N
    constexpr int NRG = BM / TM;          // threads along M
    static_assert(NCG * NRG == 128, "block must be 128 threads");
    constexpr int BK = 32;
    constexpr int XS = BM + 4;

    __shared__ float Xt[BK][XS];          // transposed, row-swizzled
    __shared__ float Ws[BK][DOUT];

    int tid = threadIdx.x;
    int tx = tid % NCG;
    int ty = tid / NCG;
    int row0 = blockIdx.x * BM;

    float acc[TM][4 * QN];
    #pragma unroll
    for (int r = 0; r < TM; r++)
        #pragma unroll
        for (int c = 0; c < 4 * QN; c++) acc[r][c] = 0.f;

    for (int k0 = 0; k0 < DIN; k0 += BK) {
        // stage X transposed: logical Xt[c][r] at Xt[c][r ^ (((c>>2)&3)<<3)]
        #pragma unroll
        for (int i = tid; i < BM * (BK / 4); i += 128) {
            int r  = i >> 3;
            int c4 = (i & 7) << 2;
            int rg = row0 + r;
            float4 v = make_float4(0.f, 0.f, 0.f, 0.f);
            if (rg < n) v = *(const float4*)&X[(size_t)rg * DIN + k0 + c4];
            int rs = r ^ ((i & 3) << 3);  // ((c>>2)&3) == i&3 for all 4 c's
            Xt[c4 + 0][rs] = v.x;
            Xt[c4 + 1][rs] = v.y;
            Xt[c4 + 2][rs] = v.z;
            Xt[c4 + 3][rs] = v.w;
        }
        #pragma unroll
        for (int i = tid; i < BK * (DOUT / 4); i += 128) {
            int r  = i / (DOUT / 4);
            int c4 = (i % (DOUT / 4)) << 2;
            *(float4*)&Ws[r][c4] = *(const float4*)&W[(size_t)(k0 + r) * DOUT + c4];
        }
        __syncthreads();

        #pragma unroll 4
        for (int k = 0; k < BK; k++) {
            int rr = (ty * TM) ^ (((k >> 2) & 3) << 3);
            float xv[TM];
            *(float4*)&xv[0] = *(const float4*)&Xt[k][rr];
            *(float4*)&xv[4] = *(const float4*)&Xt[k][rr + 4];
            float wv[4 * QN];
            #pragma unroll
            for (int q = 0; q < QN; q++)
                *(float4*)&wv[q * 4] = *(const float4*)&Ws[k][(tx + q * NCG) * 4];
            #pragma unroll
            for (int r = 0; r < TM; r++)
                #pragma unroll
                for (int c = 0; c < 4 * QN; c++)
                    acc[r][c] += xv[r] * wv[c];
        }
        __syncthreads();
    }

    #pragma unroll
    for (int r = 0; r < TM; r++) {
        int rg = row0 + ty * TM + r;
        if (rg < n) {
            float di = dinv[rg];
            #pragma unroll
            for (int q = 0; q < QN; q++) {
                __half2 p0 = __floats2half2_rn(acc[r][q * 4 + 0] * di, acc[r][q * 4 + 1] * di);
                __half2 p1 = __floats2half2_rn(acc[r][q * 4 + 2] * di, acc[r][q * 4 + 3] * di);
                uint2 w;
                w.x = *reinterpret_cast<unsigned int*>(&p0);
                w.y = *reinterpret_cast<unsigned int*>(&p1);
                *(uint2*)&G[(size_t)rg * DOUT + (tx + q * NCG) * 4] = w;
            }
        }
    }
}

// ---------------- aggregation: h[i] = tanh(dinv[i]*(sum_e G[src_e] + G[i]) + b) ----------------
// G fp16 [n,DOUT]; each lane owns 4 halves (8B gathers); fp32 accumulate; fp32 output.
template<int DOUT>
__global__ void agg_kernel(const __half* __restrict__ g, const float* __restrict__ dinv,
                           const int* __restrict__ rowptr, const int* __restrict__ esrc,
                           const float* __restrict__ bias, float* __restrict__ out, int n) {
    constexpr int LPN = DOUT / 4;           // lanes per node
    constexpr int NPW = 64 / LPN;           // nodes per wave
    int wave = threadIdx.x >> 6;
    int lane = threadIdx.x & 63;
    int sub  = lane / LPN;
    int cl   = lane % LPN;                  // 4-half chunk index
    int node = (blockIdx.x * (blockDim.x >> 6) + wave) * NPW + sub;
    if (node >= n) return;

    const uint2* g2 = (const uint2*)g;      // 4 halves per element
    auto fetch = [&](int s, float4& a) {
        uint2 v = g2[(size_t)s * LPN + cl];
        __half2 h0 = *reinterpret_cast<__half2*>(&v.x);
        __half2 h1 = *reinterpret_cast<__half2*>(&v.y);
        float2 f0 = __half22float2(h0);
        float2 f1 = __half22float2(h1);
        a.x += f0.x; a.y += f0.y; a.z += f1.x; a.w += f1.y;
    };

    float4 acc = make_float4(0.f, 0.f, 0.f, 0.f);
    fetch(node, acc);                       // self-loop term

    int e = rowptr[node], end = rowptr[node + 1];
    for (; e + 4 <= end; e += 4) {
        int s0 = esrc[e], s1 = esrc[e + 1], s2 = esrc[e + 2], s3 = esrc[e + 3];
        fetch(s0, acc); fetch(s1, acc); fetch(s2, acc); fetch(s3, acc);
    }
    for (; e < end; e++) fetch(esrc[e], acc);

    float di = dinv[node];
    float4 b = *(const float4*)&bias[cl * 4];
    float4 o;
    o.x = tanhf(di * acc.x + b.x);
    o.y = tanhf(di * acc.y + b.y);
    o.z = tanhf(di * acc.z + b.z);
    o.w = tanhf(di * acc.w + b.w);
    *(float4*)&out[(size_t)node * DOUT + cl * 4] = o;
}

// ---------------- classifier: out = H @ Wc + bc  (32 -> 86) ----------------
__global__ __launch_bounds__(256) void cls_kernel(
        const float* __restrict__ H, const float* __restrict__ Wc,
        const float* __restrict__ bc, float* __restrict__ out, int n) {
    constexpr int DIN = 32, DOUT = 86, RPB = 64;
    __shared__ float Hs[RPB][DIN + 4];
    __shared__ float Ws[DIN][DOUT];
    __shared__ float bs[DOUT];
    int tid = threadIdx.x;
    int row0 = blockIdx.x * RPB;
    for (int i = tid; i < DIN * DOUT; i += 256) Ws[i / DOUT][i % DOUT] = Wc[i];
    if (tid < DOUT) bs[tid] = bc[tid];
    for (int i = tid; i < RPB * (DIN / 4); i += 256) {
        int r = i >> 3, c4 = (i & 7) << 2;
        int rg = row0 + r;
        float4 v = make_float4(0.f, 0.f, 0.f, 0.f);
        if (rg < n) v = *(const float4*)&H[(size_t)rg * DIN + c4];
        *(float4*)&Hs[r][c4] = v;
    }
    __syncthreads();
    for (int idx = tid; idx < RPB * DOUT; idx += 256) {
        int r = idx / DOUT, c = idx - r * DOUT;
        float a = bs[c];
        #pragma unroll
        for (int k = 0; k < DIN; k++) a += Hs[r][k] * Ws[k][c];
        int rg = row0 + r;
        if (rg < n) out[(size_t)rg * DOUT + c] = a;
    }
}

extern "C" void kernel_launch(void* const* d_in, const int* in_sizes, int n_in,
                              void* d_out, int out_size, void* d_ws, size_t ws_size,
                              hipStream_t stream) {
    const float* x  = (const float*)d_in[0];
    const int*   ei = (const int*)d_in[1];
    const float* W1 = (const float*)d_in[2];
    const float* b1 = (const float*)d_in[3];
    const float* W2 = (const float*)d_in[4];
    const float* b2 = (const float*)d_in[5];
    const float* W3 = (const float*)d_in[6];
    const float* b3 = (const float*)d_in[7];
    const float* Wc = (const float*)d_in[8];
    const float* bc = (const float*)d_in[9];

    const int n = in_sizes[0] / 256;     // 100000
    const int E = in_sizes[1] / 2;       // 1600000
    const int* src = ei;
    const int* dst = ei + E;

    char* ws = (char*)d_ws;
    size_t off = 0;
    auto alloc = [&](size_t bytes) {
        void* p = ws + off;
        off = (off + bytes + 255) & ~(size_t)255;
        return p;
    };
    float*  dinv    = (float*)alloc((size_t)n * 4);
    int*    count   = (int*)  alloc((size_t)n * 4);
    int*    rowptr  = (int*)  alloc((size_t)(n + 1) * 4);
    int*    cursor  = (int*)  alloc((size_t)n * 4);
    int*    blocksum= (int*)  alloc(1024 * 4);
    int*    blockoff= (int*)  alloc(1024 * 4);
    int*    esrc    = (int*)  alloc((size_t)E * 4);
    __half* Gh      = (__half*)alloc((size_t)n * 128 * 2);  // fp16 gather buffer
    float*  Hf      = (float*)alloc((size_t)n * 128 * 4);   // fp32 activations

    float* outp = (float*)d_out;             // [n, 86]
    float* h3   = outp + (size_t)n * 86;     // [n, 32] (second tuple output)

    hipMemsetAsync(count, 0, (size_t)n * 4, stream);
    hipMemsetAsync(cursor, 0, (size_t)n * 4, stream);

    int eblocks = (E + 255) / 256;
    count_kernel<<<eblocks, 256, 0, stream>>>(dst, count, E);
    int nb = (n + 1023) / 1024;
    scan1_kernel<<<nb, 1024, 0, stream>>>(count, rowptr, dinv, blocksum, n);
    scan2_kernel<<<1, 1024, 0, stream>>>(blocksum, blockoff, rowptr, nb, n, E);
    scan3_kernel<<<(n + 255) / 256, 256, 0, stream>>>(rowptr, count, blockoff, n);
    scatter_kernel<<<eblocks, 256, 0, stream>>>(src, dst, rowptr, cursor, esrc, E);

    // layer 1: 256 -> 128   (BM=64, 2 col-quads)
    matmul_scale_kernel<256, 128, 2, 64><<<(n + 63) / 64, 128, 0, stream>>>(x, W1, dinv, Gh, n);
    agg_kernel<128><<<(n + 7) / 8, 256, 0, stream>>>(Gh, dinv, rowptr, esrc, b1, Hf, n);
    // layer 2: 128 -> 64    (BM=64, 1 quad)
    matmul_scale_kernel<128, 64, 1, 64><<<(n + 63) / 64, 128, 0, stream>>>(Hf, W2, dinv, Gh, n);
    agg_kernel<64><<<(n + 15) / 16, 256, 0, stream>>>(Gh, dinv, rowptr, esrc, b2, Hf, n);
    // layer 3: 64 -> 32     (BM=128, 1 quad)
    matmul_scale_kernel<64, 32, 1, 128><<<(n + 127) / 128, 128, 0, stream>>>(Hf, W3, dinv, Gh, n);
    agg_kernel<32><<<(n + 31) / 32, 256, 0, stream>>>(Gh, dinv, rowptr, esrc, b3, h3, n);
    // classifier: 32 -> 86
    cls_kernel<<<(n + 63) / 64, 256, 0, stream>>>(h3, Wc, bc, outp, n);
}

// Round 7
// 580.856 us; speedup vs baseline: 1.2775x; 1.1753x over previous
//
#include <hip/hip_runtime.h>
#include <hip/hip_bf16.h>
#include <hip/hip_fp16.h>

typedef _Float16 f16;
typedef f16 f16x4 __attribute__((ext_vector_type(4)));
typedef f16 f16x8 __attribute__((ext_vector_type(8)));
typedef float f32x4 __attribute__((ext_vector_type(4)));

// ---------------- CSR build ----------------

__global__ void count_kernel(const int* __restrict__ dst, int* __restrict__ count, int E) {
    int e = blockIdx.x * blockDim.x + threadIdx.x;
    if (e < E) atomicAdd(&count[dst[e]], 1);
}

__global__ void scan1_kernel(const int* __restrict__ count, int* __restrict__ incl,
                             float* __restrict__ dinv, int* __restrict__ blocksum, int n) {
    __shared__ int lds[1024];
    int t = threadIdx.x;
    int i = blockIdx.x * 1024 + t;
    int v = (i < n) ? count[i] : 0;
    if (i < n) dinv[i] = rsqrtf((float)(v + 1));
    lds[t] = v;
    __syncthreads();
    for (int off = 1; off < 1024; off <<= 1) {
        int add = (t >= off) ? lds[t - off] : 0;
        __syncthreads();
        lds[t] += add;
        __syncthreads();
    }
    if (i < n) incl[i] = lds[t];
    if (t == 1023) blocksum[blockIdx.x] = lds[1023];
}

__global__ void scan2_kernel(const int* __restrict__ blocksum, int* __restrict__ blockoff,
                             int* __restrict__ rowptr, int nb, int n, int E) {
    __shared__ int lds[1024];
    int t = threadIdx.x;
    int v = (t < nb) ? blocksum[t] : 0;
    lds[t] = v;
    __syncthreads();
    for (int off = 1; off < 1024; off <<= 1) {
        int add = (t >= off) ? lds[t - off] : 0;
        __syncthreads();
        lds[t] += add;
        __syncthreads();
    }
    if (t < nb) blockoff[t] = lds[t] - v;   // exclusive
    if (t == 0) rowptr[n] = E;
}

__global__ void scan3_kernel(int* __restrict__ rowptr, const int* __restrict__ count,
                             const int* __restrict__ blockoff, int n) {
    int i = blockIdx.x * blockDim.x + threadIdx.x;
    if (i < n) rowptr[i] = rowptr[i] - count[i] + blockoff[i >> 10];
}

__global__ void scatter_kernel(const int* __restrict__ src, const int* __restrict__ dst,
                               const int* __restrict__ rowptr, int* __restrict__ cursor,
                               int* __restrict__ esrc, int E) {
    int e = blockIdx.x * blockDim.x + threadIdx.x;
    if (e < E) {
        int d = dst[e];
        int pos = rowptr[d] + atomicAdd(&cursor[d], 1);
        esrc[pos] = src[e];
    }
}

// ---------------- MFMA GEMM: G = f16( (X @ W) * dinv[row] ) ----------------
// X [n,DIN] fp32 row-major, W [DIN,DOUT] fp32 row-major; fp32->fp16 conversion
// happens in registers during LDS staging (no extra global pass).
// 4 waves; wave-tile 64 x WN via 16x16x32_f16 MFMA (RF=4 row frags, CF col frags).
// LDS tiles padded to 80B row stride: fragment ds_read_b128 rows hit rotating
// bank groups (<=2-way alias = free); A and W^T both read as single b128.
template<int DIN, int DOUT, int WAVES_M>
__global__ __launch_bounds__(256) void mfma_gemm_kernel(
        const float* __restrict__ X, const float* __restrict__ W,
        const float* __restrict__ dinv, f16* __restrict__ G, int n) {
    constexpr int WAVES_N = 4 / WAVES_M;
    constexpr int BM = WAVES_M * 64;
    constexpr int WN = DOUT / WAVES_N;     // 64 or 32
    constexpr int RF = 4;                  // row fragments (64/16)
    constexpr int CF = WN / 16;            // col fragments
    constexpr int BK = 32;
    constexpr int LDK = BK + 8;            // padded stride in halves (80B)
    constexpr int KPT = BK * DOUT / 256;   // W k-elements per thread (16/8/4)

    __shared__ f16 As[BM][LDK];            // A tile, row-major [m][k]
    __shared__ f16 Bs[DOUT][LDK];          // W tile TRANSPOSED: [n][k]

    int tid  = threadIdx.x;
    int lane = tid & 63;
    int w    = tid >> 6;
    int wy   = w / WAVES_N;
    int wx   = w % WAVES_N;
    int row0 = blockIdx.x * BM;
    int l15  = lane & 15;
    int kq   = lane >> 4;                  // 0..3

    f32x4 acc[RF][CF];
    #pragma unroll
    for (int i = 0; i < RF; i++)
        #pragma unroll
        for (int j = 0; j < CF; j++)
            acc[i][j] = (f32x4){0.f, 0.f, 0.f, 0.f};

    for (int k0 = 0; k0 < DIN; k0 += BK) {
        // stage A: 8 consecutive threads cover one row's 128B (coalesced),
        // convert to fp16, write 8B to LDS.
        #pragma unroll
        for (int i = tid; i < BM * 8; i += 256) {
            int r  = i >> 3;
            int c4 = (i & 7) << 2;
            int rg = row0 + r;
            float4 v = make_float4(0.f, 0.f, 0.f, 0.f);
            if (rg < n) v = *(const float4*)&X[(size_t)rg * DIN + k0 + c4];
            f16x4 h = { (f16)v.x, (f16)v.y, (f16)v.z, (f16)v.w };
            *(f16x4*)&As[r][c4] = h;
        }
        // stage W transposed: thread owns column nc, KPT consecutive k's.
        // Global reads coalesced across lanes (consecutive nc); LDS write is
        // one contiguous b128/b64 per 8/4 halves.
        {
            int nc = tid % DOUT;
            int kb = (tid / DOUT) * KPT;
            f16 tmp[KPT];
            #pragma unroll
            for (int j = 0; j < KPT; j++)
                tmp[j] = (f16)W[(size_t)(k0 + kb + j) * DOUT + nc];
            if constexpr (KPT == 16) {
                *(f16x8*)&Bs[nc][kb]     = *(f16x8*)&tmp[0];
                *(f16x8*)&Bs[nc][kb + 8] = *(f16x8*)&tmp[8];
            } else if constexpr (KPT == 8) {
                *(f16x8*)&Bs[nc][kb]     = *(f16x8*)&tmp[0];
            } else {
                *(f16x4*)&Bs[nc][kb]     = *(f16x4*)&tmp[0];
            }
        }
        __syncthreads();

        // fragments: A lane l -> row (l&15), k = (l>>4)*8+j ; B lane l -> col
        // (l&15), k = (l>>4)*8+j.  Both are single 16B contiguous LDS reads.
        f16x8 a[RF], b[CF];
        #pragma unroll
        for (int i = 0; i < RF; i++)
            a[i] = *(f16x8*)&As[wy * 64 + i * 16 + l15][kq * 8];
        #pragma unroll
        for (int j = 0; j < CF; j++)
            b[j] = *(f16x8*)&Bs[wx * WN + j * 16 + l15][kq * 8];
        #pragma unroll
        for (int i = 0; i < RF; i++)
            #pragma unroll
            for (int j = 0; j < CF; j++)
                acc[i][j] = __builtin_amdgcn_mfma_f32_16x16x32_f16(a[i], b[j], acc[i][j], 0, 0, 0);
        __syncthreads();
    }

    // epilogue: C/D layout col = lane&15, row = (lane>>4)*4 + reg
    #pragma unroll
    for (int i = 0; i < RF; i++) {
        #pragma unroll
        for (int r = 0; r < 4; r++) {
            int row = row0 + wy * 64 + i * 16 + (lane >> 4) * 4 + r;
            if (row < n) {
                float di = dinv[row];
                #pragma unroll
                for (int j = 0; j < CF; j++) {
                    int col = wx * WN + j * 16 + l15;
                    G[(size_t)row * DOUT + col] = (f16)(acc[i][j][r] * di);
                }
            }
        }
    }
}

// ---------------- aggregation: h[i] = tanh(dinv[i]*(sum_e G[src_e] + G[i]) + b) ----------------
// G fp16 [n,DOUT]; each lane owns 4 halves (8B gathers); fp32 accumulate; fp32 output.
template<int DOUT>
__global__ void agg_kernel(const __half* __restrict__ g, const float* __restrict__ dinv,
                           const int* __restrict__ rowptr, const int* __restrict__ esrc,
                           const float* __restrict__ bias, float* __restrict__ out, int n) {
    constexpr int LPN = DOUT / 4;           // lanes per node
    constexpr int NPW = 64 / LPN;           // nodes per wave
    int wave = threadIdx.x >> 6;
    int lane = threadIdx.x & 63;
    int sub  = lane / LPN;
    int cl   = lane % LPN;                  // 4-half chunk index
    int node = (blockIdx.x * (blockDim.x >> 6) + wave) * NPW + sub;
    if (node >= n) return;

    const uint2* g2 = (const uint2*)g;      // 4 halves per element
    auto fetch = [&](int s, float4& a) {
        uint2 v = g2[(size_t)s * LPN + cl];
        __half2 h0 = *reinterpret_cast<__half2*>(&v.x);
        __half2 h1 = *reinterpret_cast<__half2*>(&v.y);
        float2 f0 = __half22float2(h0);
        float2 f1 = __half22float2(h1);
        a.x += f0.x; a.y += f0.y; a.z += f1.x; a.w += f1.y;
    };

    float4 acc = make_float4(0.f, 0.f, 0.f, 0.f);
    fetch(node, acc);                       // self-loop term

    int e = rowptr[node], end = rowptr[node + 1];
    for (; e + 4 <= end; e += 4) {
        int s0 = esrc[e], s1 = esrc[e + 1], s2 = esrc[e + 2], s3 = esrc[e + 3];
        fetch(s0, acc); fetch(s1, acc); fetch(s2, acc); fetch(s3, acc);
    }
    for (; e < end; e++) fetch(esrc[e], acc);

    float di = dinv[node];
    float4 b = *(const float4*)&bias[cl * 4];
    float4 o;
    o.x = tanhf(di * acc.x + b.x);
    o.y = tanhf(di * acc.y + b.y);
    o.z = tanhf(di * acc.z + b.z);
    o.w = tanhf(di * acc.w + b.w);
    *(float4*)&out[(size_t)node * DOUT + cl * 4] = o;
}

// ---------------- classifier: out = H @ Wc + bc  (32 -> 86) ----------------
__global__ __launch_bounds__(256) void cls_kernel(
        const float* __restrict__ H, const float* __restrict__ Wc,
        const float* __restrict__ bc, float* __restrict__ out, int n) {
    constexpr int DIN = 32, DOUT = 86, RPB = 64;
    __shared__ float Hs[RPB][DIN + 4];
    __shared__ float Ws[DIN][DOUT];
    __shared__ float bs[DOUT];
    int tid = threadIdx.x;
    int row0 = blockIdx.x * RPB;
    for (int i = tid; i < DIN * DOUT; i += 256) Ws[i / DOUT][i % DOUT] = Wc[i];
    if (tid < DOUT) bs[tid] = bc[tid];
    for (int i = tid; i < RPB * (DIN / 4); i += 256) {
        int r = i >> 3, c4 = (i & 7) << 2;
        int rg = row0 + r;
        float4 v = make_float4(0.f, 0.f, 0.f, 0.f);
        if (rg < n) v = *(const float4*)&H[(size_t)rg * DIN + c4];
        *(float4*)&Hs[r][c4] = v;
    }
    __syncthreads();
    for (int idx = tid; idx < RPB * DOUT; idx += 256) {
        int r = idx / DOUT, c = idx - r * DOUT;
        float a = bs[c];
        #pragma unroll
        for (int k = 0; k < DIN; k++) a += Hs[r][k] * Ws[k][c];
        int rg = row0 + r;
        if (rg < n) out[(size_t)rg * DOUT + c] = a;
    }
}

extern "C" void kernel_launch(void* const* d_in, const int* in_sizes, int n_in,
                              void* d_out, int out_size, void* d_ws, size_t ws_size,
                              hipStream_t stream) {
    const float* x  = (const float*)d_in[0];
    const int*   ei = (const int*)d_in[1];
    const float* W1 = (const float*)d_in[2];
    const float* b1 = (const float*)d_in[3];
    const float* W2 = (const float*)d_in[4];
    const float* b2 = (const float*)d_in[5];
    const float* W3 = (const float*)d_in[6];
    const float* b3 = (const float*)d_in[7];
    const float* Wc = (const float*)d_in[8];
    const float* bc = (const float*)d_in[9];

    const int n = in_sizes[0] / 256;     // 100000
    const int E = in_sizes[1] / 2;       // 1600000
    const int* src = ei;
    const int* dst = ei + E;

    char* ws = (char*)d_ws;
    size_t off = 0;
    auto alloc = [&](size_t bytes) {
        void* p = ws + off;
        off = (off + bytes + 255) & ~(size_t)255;
        return p;
    };
    float*  dinv    = (float*)alloc((size_t)n * 4);
    int*    count   = (int*)  alloc((size_t)n * 4);
    int*    rowptr  = (int*)  alloc((size_t)(n + 1) * 4);
    int*    cursor  = (int*)  alloc((size_t)n * 4);
    int*    blocksum= (int*)  alloc(1024 * 4);
    int*    blockoff= (int*)  alloc(1024 * 4);
    int*    esrc    = (int*)  alloc((size_t)E * 4);
    __half* Gh      = (__half*)alloc((size_t)n * 128 * 2);  // fp16 gather buffer
    float*  Hf      = (float*)alloc((size_t)n * 128 * 4);   // fp32 activations

    float* outp = (float*)d_out;             // [n, 86]
    float* h3   = outp + (size_t)n * 86;     // [n, 32] (second tuple output)

    hipMemsetAsync(count, 0, (size_t)n * 4, stream);
    hipMemsetAsync(cursor, 0, (size_t)n * 4, stream);

    int eblocks = (E + 255) / 256;
    count_kernel<<<eblocks, 256, 0, stream>>>(dst, count, E);
    int nb = (n + 1023) / 1024;
    scan1_kernel<<<nb, 1024, 0, stream>>>(count, rowptr, dinv, blocksum, n);
    scan2_kernel<<<1, 1024, 0, stream>>>(blocksum, blockoff, rowptr, nb, n, E);
    scan3_kernel<<<(n + 255) / 256, 256, 0, stream>>>(rowptr, count, blockoff, n);
    scatter_kernel<<<eblocks, 256, 0, stream>>>(src, dst, rowptr, cursor, esrc, E);

    // layer 1: 256 -> 128   (BM=128, waves 2x2)
    mfma_gemm_kernel<256, 128, 2><<<(n + 127) / 128, 256, 0, stream>>>(x, W1, dinv, (f16*)Gh, n);
    agg_kernel<128><<<(n + 7) / 8, 256, 0, stream>>>(Gh, dinv, rowptr, esrc, b1, Hf, n);
    // layer 2: 128 -> 64    (BM=256, waves 4x1)
    mfma_gemm_kernel<128, 64, 4><<<(n + 255) / 256, 256, 0, stream>>>(Hf, W2, dinv, (f16*)Gh, n);
    agg_kernel<64><<<(n + 15) / 16, 256, 0, stream>>>(Gh, dinv, rowptr, esrc, b2, Hf, n);
    // layer 3: 64 -> 32     (BM=256, waves 4x1)
    mfma_gemm_kernel<64, 32, 4><<<(n + 255) / 256, 256, 0, stream>>>(Hf, W3, dinv, (f16*)Gh, n);
    agg_kernel<32><<<(n + 31) / 32, 256, 0, stream>>>(Gh, dinv, rowptr, esrc, b3, h3, n);
    // classifier: 32 -> 86
    cls_kernel<<<(n + 63) / 64, 256, 0, stream>>>(h3, Wc, bc, outp, n);
}